// Round 6
// baseline (2220.507 us; speedup 1.0000x reference)
//
#include <hip/hip_runtime.h>
#include <hip/hip_bf16.h>
#include <math.h>

#define B_ 16
#define S_ 512
#define E_ 300
#define H_ 512
#define V_ 10000
#define BS_ (B_ * S_)  // 8192

#define GPB 8            // blocks per batch (k-split)
#define KPB (H_ / GPB)   // 64 k per block
#define NBLK (B_ * GPB)  // 128 blocks in the scan

typedef __attribute__((ext_vector_type(4))) float f32x4;
typedef __attribute__((ext_vector_type(8))) short bf16x8;

// ---------------------------------------------------------------------------
// K0: invalidate exchange tags (prev call leaves tags 0..511 that would match)
// ---------------------------------------------------------------------------
__global__ __launch_bounds__(256) void k0_init(unsigned long long* __restrict__ part) {
  const int idx = blockIdx.x * 256 + threadIdx.x;
  part[idx] = 0xFFFFFFFF00000000ull;
}

// ---------------------------------------------------------------------------
// K1: xw[bs,h] = sum_e x[bs,e] * W_ih[h,e] + b_ih[h] + b_hh[h]
// ---------------------------------------------------------------------------
__global__ __launch_bounds__(256) void k1_xw(const float* __restrict__ x,
                                             const float* __restrict__ W_ih,
                                             const float* __restrict__ b_ih,
                                             const float* __restrict__ b_hh,
                                             float* __restrict__ xw) {
  __shared__ float As[16][301];
  __shared__ float Ws[16][301];
  const int row0 = blockIdx.x * 16;
  const int col0 = blockIdx.y * 16;
  const int tid = threadIdx.x;
  for (int idx = tid; idx < 16 * E_; idx += 256) {
    int r = idx / E_, c = idx - r * E_;
    As[r][c] = x[(size_t)(row0 + r) * E_ + c];
    Ws[r][c] = W_ih[(size_t)(col0 + r) * E_ + c];
  }
  __syncthreads();
  const int i = tid >> 4, j = tid & 15;
  float acc = 0.f;
#pragma unroll 4
  for (int e = 0; e < E_; ++e) acc += As[i][e] * Ws[j][e];
  const int h = col0 + j;
  xw[(size_t)(row0 + i) * H_ + h] = acc + b_ih[h] + b_hh[h];
}

__device__ __forceinline__ unsigned long long pload(
    const unsigned long long* p) {
  return __hip_atomic_load(p, __ATOMIC_RELAXED, __HIP_MEMORY_SCOPE_AGENT);
}

// ---------------------------------------------------------------------------
// K2: scan. Block (b,g) owns k-range [g*64, g*64+64). 512 threads, thread=j
// holds W_hh[j][g*64 .. +64) in 64 VGPRs, made remat-proof by an opaque
// asm register barrier (the compiler otherwise re-loads W inside the loop —
// rounds 4/5 showed VGPR_Count 80/48, i.e. W streamed from L2 every step).
// Per step:
//   dot: 16 x (LDS-broadcast float4 of h) * w  -> partial p for row j
//   publish (t<<32 | f32(p)) as one relaxed agent u64 store
//   own-range threads (j in k-range): poll 7 partners concurrently (1 MALL
//   RT), tot = sum, h = tanh(xw+tot), write hl[nxt][j-g*64] + hs slice
//   ONE __syncthreads per step.
// h is only needed for the block's own k-range => hl is 64 floats.
// Slot reuse at distance 2 race-free (partner consumed t before publishing
// t+1, which we consume before overwriting with t+2).
// ---------------------------------------------------------------------------
__global__ __launch_bounds__(512, 4) void k2_scan(
    const float* __restrict__ xw, const float* __restrict__ W_hh,
    float* __restrict__ hs, unsigned long long* __restrict__ part) {
  const int b = blockIdx.x >> 3;
  const int g = blockIdx.x & 7;
  const int j = threadIdx.x;  // 0..511 output row
  const int tid = threadIdx.x;

  // W row-slice into registers, then pin with an opaque asm barrier.
  float w[KPB];
  {
    const float* wrow = &W_hh[(size_t)j * H_ + g * KPB];
#pragma unroll
    for (int k = 0; k < KPB / 4; ++k) {
      const float4 t = *(const float4*)&wrow[k * 4];
      w[k * 4 + 0] = t.x; w[k * 4 + 1] = t.y;
      w[k * 4 + 2] = t.z; w[k * 4 + 3] = t.w;
    }
  }
#pragma unroll
  for (int k = 0; k < KPB; ++k) asm volatile("" : "+v"(w[k]));

  __shared__ float hl[2][KPB];
  if (tid < KPB) hl[0][tid] = 0.f;

  unsigned long long* const pbase = part + (size_t)b * (2 * GPB * H_);
  const unsigned in_range = (unsigned)(tid - g * KPB) < (unsigned)KPB;

  float xwv = xw[(size_t)b * S_ * H_ + j];
  __syncthreads();

  for (int t = 0; t < S_; ++t) {
    const int cur = t & 1;
    const int slot = t & 1;
    // dot over own k-range; h broadcast from LDS (all lanes same address)
    float acc = 0.f;
#pragma unroll
    for (int k = 0; k < KPB / 4; ++k) {
      const float4 hv = *(const float4*)&hl[cur][k * 4];
      acc += w[k * 4 + 0] * hv.x + w[k * 4 + 1] * hv.y +
             w[k * 4 + 2] * hv.z + w[k * 4 + 3] * hv.w;
    }
    // publish tagged partial
    const unsigned long long pk =
        ((unsigned long long)(unsigned)t << 32) |
        (unsigned long long)(unsigned)__float_as_uint(acc);
    __hip_atomic_store(&pbase[(slot * GPB + g) * H_ + j], pk, __ATOMIC_RELAXED,
                       __HIP_MEMORY_SCOPE_AGENT);

    // prefetch next step's xw while partners compute
    const int tn = (t + 1 < S_) ? t + 1 : t;
    const float xw_next = xw[((size_t)b * S_ + tn) * H_ + j];

    if (in_range) {
      const unsigned ut = (unsigned)t;
      const unsigned long long* ap[GPB - 1];
      unsigned long long v[GPB - 1];
#pragma unroll
      for (int q = 0; q < GPB - 1; ++q) {
        const int pg = (g + 1 + q) & 7;
        ap[q] = &pbase[(slot * GPB + pg) * H_ + j];
        v[q] = pload(ap[q]);  // issue all 7 concurrently
      }
      float tot = acc;
#pragma unroll
      for (int q = 0; q < GPB - 1; ++q) {
        while ((unsigned)(v[q] >> 32) != ut) v[q] = pload(ap[q]);
        tot += __uint_as_float((unsigned)v[q]);
      }
      const float hn = tanhf(xwv + tot);
      hl[cur ^ 1][j - g * KPB] = hn;
      hs[((size_t)b * S_ + t) * H_ + j] = hn;  // each block writes its slice
    }
    xwv = xw_next;
    __syncthreads();
  }
}

// ---------------------------------------------------------------------------
// K5: split f32 -> bf16 hi + bf16 lo (RTN both; lo = f - hi).
// ---------------------------------------------------------------------------
__device__ __forceinline__ unsigned short bf16_rtn(float f) {
  unsigned u = __float_as_uint(f);
  return (unsigned short)((u + 0x7FFFu + ((u >> 16) & 1u)) >> 16);
}
__global__ __launch_bounds__(256) void k5_split(const float* __restrict__ src,
                                                unsigned short* __restrict__ hi,
                                                unsigned short* __restrict__ lo,
                                                int n4) {
  const int i = blockIdx.x * 256 + threadIdx.x;
  if (i >= n4) return;
  const float4 f = *(const float4*)&src[i * 4];
  unsigned short h[4], l[4];
  const float ff[4] = {f.x, f.y, f.z, f.w};
#pragma unroll
  for (int k = 0; k < 4; ++k) {
    h[k] = bf16_rtn(ff[k]);
    const float fh = __uint_as_float((unsigned)h[k] << 16);
    l[k] = bf16_rtn(ff[k] - fh);
  }
  *(ushort4*)&hi[i * 4] = make_ushort4(h[0], h[1], h[2], h[3]);
  *(ushort4*)&lo[i * 4] = make_ushort4(l[0], l[1], l[2], l[3]);
}

// ---------------------------------------------------------------------------
// K3: logits = hs @ W_fc^T + b_fc via bf16 hi/lo split MFMA (hh+hl+lh).
// 128x128 tile, 2x2 waves, 64x64/wave, BK=32, LDS row stride 40 shorts.
// ---------------------------------------------------------------------------
__global__ __launch_bounds__(256) void k3_logits(
    const unsigned short* __restrict__ Ahi, const unsigned short* __restrict__ Alo,
    const unsigned short* __restrict__ Bhi, const unsigned short* __restrict__ Blo,
    const float* __restrict__ b_fc, float* __restrict__ out) {
  __shared__ unsigned short Ah[128 * 40], Al[128 * 40];
  __shared__ unsigned short Bh[128 * 40], Bl[128 * 40];
  const int m0 = blockIdx.x * 128;
  const int n0 = blockIdx.y * 128;
  const int tid = threadIdx.x;
  const int lane = tid & 63;
  const int wave = tid >> 6;
  const int wm = wave >> 1, wn = wave & 1;
  const int lr = lane & 15;
  const int lk = (lane >> 4) * 8;

  f32x4 acc[4][4];
#pragma unroll
  for (int mi = 0; mi < 4; ++mi)
#pragma unroll
    for (int ni = 0; ni < 4; ++ni) acc[mi][ni] = (f32x4)0.0f;

  const int sr = tid >> 2;
  const int sq = (tid & 3) * 8;

  for (int k0 = 0; k0 < H_; k0 += 32) {
    __syncthreads();
#pragma unroll
    for (int it = 0; it < 2; ++it) {
      const int r = sr + it * 64;
      const size_t am = (size_t)(m0 + r) * H_ + k0 + sq;
      const int brow = (n0 + r < V_) ? (n0 + r) : (V_ - 1);
      const size_t bm = (size_t)brow * H_ + k0 + sq;
      *(float4*)&Ah[r * 40 + sq] = *(const float4*)&Ahi[am];
      *(float4*)&Al[r * 40 + sq] = *(const float4*)&Alo[am];
      *(float4*)&Bh[r * 40 + sq] = *(const float4*)&Bhi[bm];
      *(float4*)&Bl[r * 40 + sq] = *(const float4*)&Blo[bm];
    }
    __syncthreads();

    bf16x8 ah[4], al[4], bh[4], bl[4];
#pragma unroll
    for (int i = 0; i < 4; ++i) {
      ah[i] = *(const bf16x8*)&Ah[(wm * 64 + i * 16 + lr) * 40 + lk];
      al[i] = *(const bf16x8*)&Al[(wm * 64 + i * 16 + lr) * 40 + lk];
      bh[i] = *(const bf16x8*)&Bh[(wn * 64 + i * 16 + lr) * 40 + lk];
      bl[i] = *(const bf16x8*)&Bl[(wn * 64 + i * 16 + lr) * 40 + lk];
    }
#pragma unroll
    for (int mi = 0; mi < 4; ++mi)
#pragma unroll
      for (int ni = 0; ni < 4; ++ni) {
        acc[mi][ni] = __builtin_amdgcn_mfma_f32_16x16x32_bf16(
            ah[mi], bh[ni], acc[mi][ni], 0, 0, 0);
        acc[mi][ni] = __builtin_amdgcn_mfma_f32_16x16x32_bf16(
            ah[mi], bl[ni], acc[mi][ni], 0, 0, 0);
        acc[mi][ni] = __builtin_amdgcn_mfma_f32_16x16x32_bf16(
            al[mi], bh[ni], acc[mi][ni], 0, 0, 0);
      }
  }

#pragma unroll
  for (int ni = 0; ni < 4; ++ni) {
    const int v = n0 + wn * 64 + ni * 16 + lr;
    if (v >= V_) continue;
    const float bias = b_fc[v];
#pragma unroll
    for (int mi = 0; mi < 4; ++mi) {
      const int mrow = m0 + wm * 64 + mi * 16 + (lane >> 4) * 4;
#pragma unroll
      for (int r = 0; r < 4; ++r)
        out[(size_t)(mrow + r) * V_ + v] = acc[mi][ni][r] + bias;
    }
  }
}

// ---------------------------------------------------------------------------
// K4a: per-(b,v) online max+sum over S; stores (m, 1/sum).
// ---------------------------------------------------------------------------
__global__ __launch_bounds__(256) void k4_stats(const float* __restrict__ logits,
                                                float* __restrict__ stats) {
  const int g = blockIdx.x * 256 + threadIdx.x;
  const int b = g / V_;
  const int v = g - b * V_;
  const float* p = logits + (size_t)b * S_ * V_ + v;
  float m = -3.4e38f, sum = 0.f;
  for (int s = 0; s < S_; ++s) {
    const float xv = p[(size_t)s * V_];
    if (xv > m) {
      sum = sum * __expf(m - xv) + 1.f;
      m = xv;
    } else {
      sum += __expf(xv - m);
    }
  }
  stats[2 * g] = m;
  stats[2 * g + 1] = 1.f / sum;
}

// ---------------------------------------------------------------------------
// K4b: in-place normalize: out = exp(l - m) * inv_sum
// ---------------------------------------------------------------------------
__global__ __launch_bounds__(256) void k4_norm(float* __restrict__ logits,
                                               const float* __restrict__ stats) {
  const size_t idx = (size_t)blockIdx.x * 256 + threadIdx.x;
  const int v = (int)(idx % V_);
  const int b = (int)(idx / ((size_t)S_ * V_));
  const int g = b * V_ + v;
  const float m = stats[2 * g];
  const float inv = stats[2 * g + 1];
  logits[idx] = __expf(logits[idx] - m) * inv;
}

extern "C" void kernel_launch(void* const* d_in, const int* in_sizes, int n_in,
                              void* d_out, int out_size, void* d_ws,
                              size_t ws_size, hipStream_t stream) {
  const float* x    = (const float*)d_in[0];
  const float* W_ih = (const float*)d_in[1];
  const float* W_hh = (const float*)d_in[2];
  const float* b_ih = (const float*)d_in[3];
  const float* b_hh = (const float*)d_in[4];
  const float* W_fc = (const float*)d_in[5];
  const float* b_fc = (const float*)d_in[6];
  float* out = (float*)d_out;

  // ws layout (floats): xw | hs | stats | wfc_hi | wfc_lo
  //   part (1 MB, scan-only) ALIASES wfc_hi: k0/k2 finish before k5_wfc runs
  //   hs_hi/hs_lo (bf16) ALIAS xw (dead after k2)
  float* ws = (float*)d_ws;
  float* xw    = ws;
  float* hs    = xw + (size_t)BS_ * H_;
  float* stats = hs + (size_t)BS_ * H_;
  unsigned short* wfc_hi = (unsigned short*)(stats + (size_t)2 * B_ * V_);
  unsigned short* wfc_lo = wfc_hi + (size_t)V_ * H_;
  unsigned long long* part = (unsigned long long*)wfc_hi;
  unsigned short* hs_hi = (unsigned short*)xw;
  unsigned short* hs_lo = hs_hi + (size_t)BS_ * H_;

  k0_init<<<(B_ * 2 * GPB * H_) / 256, 256, 0, stream>>>(part);
  k1_xw<<<dim3(BS_ / 16, H_ / 16), 256, 0, stream>>>(x, W_ih, b_ih, b_hh, xw);
  k2_scan<<<NBLK, 512, 0, stream>>>(xw, W_hh, hs, part);
  k5_split<<<((V_ * H_ / 4) + 255) / 256, 256, 0, stream>>>(W_fc, wfc_hi,
                                                            wfc_lo, V_ * H_ / 4);
  k5_split<<<((BS_ * H_ / 4) + 255) / 256, 256, 0, stream>>>(
      hs, hs_hi, hs_lo, BS_ * H_ / 4);
  k3_logits<<<dim3(BS_ / 128, (V_ + 127) / 128), 256, 0, stream>>>(
      hs_hi, hs_lo, wfc_hi, wfc_lo, b_fc, out);
  k4_stats<<<(B_ * V_) / 256, 256, 0, stream>>>(out, stats);
  k4_norm<<<(int)((size_t)BS_ * V_ / 256), 256, 0, stream>>>(out, stats);
}

// Round 7
// 2039.450 us; speedup vs baseline: 1.0888x; 1.0888x over previous
//
#include <hip/hip_runtime.h>
#include <hip/hip_bf16.h>
#include <math.h>

#define B_ 16
#define S_ 512
#define E_ 300
#define H_ 512
#define V_ 10000
#define BS_ (B_ * S_)  // 8192

#define NSL 16           // slices (blocks) per batch, j-split
#define JPB (H_ / NSL)   // 32 output rows per block
#define NBLK (B_ * NSL)  // 256 blocks in the scan

typedef __attribute__((ext_vector_type(4))) float f32x4;
typedef __attribute__((ext_vector_type(8))) short bf16x8;

// ---------------------------------------------------------------------------
// K0: invalidate exchange tags (prev call leaves tags 0..511 that would match)
// ---------------------------------------------------------------------------
__global__ __launch_bounds__(256) void k0_init(unsigned long long* __restrict__ part) {
  const int idx = blockIdx.x * 256 + threadIdx.x;
  part[idx] = 0xFFFFFFFF00000000ull;
}

// ---------------------------------------------------------------------------
// K1: xw[bs,h] = sum_e x[bs,e] * W_ih[h,e] + b_ih[h] + b_hh[h]
// ---------------------------------------------------------------------------
__global__ __launch_bounds__(256) void k1_xw(const float* __restrict__ x,
                                             const float* __restrict__ W_ih,
                                             const float* __restrict__ b_ih,
                                             const float* __restrict__ b_hh,
                                             float* __restrict__ xw) {
  __shared__ float As[16][301];
  __shared__ float Ws[16][301];
  const int row0 = blockIdx.x * 16;
  const int col0 = blockIdx.y * 16;
  const int tid = threadIdx.x;
  for (int idx = tid; idx < 16 * E_; idx += 256) {
    int r = idx / E_, c = idx - r * E_;
    As[r][c] = x[(size_t)(row0 + r) * E_ + c];
    Ws[r][c] = W_ih[(size_t)(col0 + r) * E_ + c];
  }
  __syncthreads();
  const int i = tid >> 4, j = tid & 15;
  float acc = 0.f;
#pragma unroll 4
  for (int e = 0; e < E_; ++e) acc += As[i][e] * Ws[j][e];
  const int h = col0 + j;
  xw[(size_t)(row0 + i) * H_ + h] = acc + b_ih[h] + b_hh[h];
}

__device__ __forceinline__ unsigned long long pload(
    const unsigned long long* p) {
  return __hip_atomic_load(p, __ATOMIC_RELAXED, __HIP_MEMORY_SCOPE_AGENT);
}

// ---------------------------------------------------------------------------
// K2: scan, j-split with LDS-resident W (instruction-major layout).
// Block (b,g) owns output rows [g*32, g*32+32). 512 threads = (j in 32) x
// (q in 16); thread (j,q) covers k in [q*32, q*32+32).
// W in LDS as Wp[i4][tid] (f32x4): each of the 8 dot reads per thread is a
// ds_read_b128 whose 64 lanes cover a contiguous 1 KB -> conflict-free by
// construction (rounds 4-6 showed the register allocator will NOT keep a
// W slice in VGPRs: VGPR_Count 80/48/52 = W streamed from L2/scratch).
// h staged per step in hp[slot][i4*16+q] (f32x4): dot reads are contiguous
// 256 B with 4-lane broadcast (conflict-free); stage writes 2-way (free).
// Exchange: q==0 publishes (t<<32|f32(h)) u64 relaxed-agent; all threads
// poll their own h word (1 concurrent MALL RT each), restage, ONE barrier.
// Slot (t&1) reuse at distance 2 is race-free: partner published tag t+1
// only after consuming tag t.
// ---------------------------------------------------------------------------
__global__ __launch_bounds__(512) void k2_scan(
    const float* __restrict__ xw, const float* __restrict__ W_hh,
    float* __restrict__ hs, unsigned long long* __restrict__ part) {
  const int b = blockIdx.x >> 4;  // batch
  const int g = blockIdx.x & 15;  // slice
  const int tid = threadIdx.x;
  const int j = tid >> 4;         // 0..31 row within slice
  const int q = tid & 15;         // k-sixteenth
  const int jg = g * JPB + j;     // global output row

  __shared__ f32x4 Wp[8 * 512];   // 64 KB, instruction-major W
  __shared__ f32x4 hp[2][128];    // 4 KB, double-buffered h

  {
    const float* wrow = &W_hh[(size_t)jg * H_ + q * 32];
#pragma unroll
    for (int i4 = 0; i4 < 8; ++i4)
      Wp[i4 * 512 + tid] = *(const f32x4*)&wrow[i4 * 4];
  }
  if (tid < 128) hp[0][tid] = (f32x4)0.f;

  // part layout: [slot][b][j_global]
  unsigned long long* const pb = part + (size_t)b * H_;

  float xwv = xw[(size_t)b * S_ * H_ + jg];  // t = 0
  __syncthreads();

  for (int t = 0; t < S_; ++t) {
    const int cur = t & 1;
    // dot: 8 x (b128 W read, b128 h broadcast, fma4)
    f32x4 a4 = (f32x4)0.f;
#pragma unroll
    for (int i4 = 0; i4 < 8; ++i4) {
      const f32x4 wv = Wp[i4 * 512 + tid];
      const f32x4 hv = hp[cur][i4 * 16 + q];
      a4 += wv * hv;
    }
    float acc = a4.x + a4.y + a4.z + a4.w;
    acc += __shfl_xor(acc, 1);
    acc += __shfl_xor(acc, 2);
    acc += __shfl_xor(acc, 4);
    acc += __shfl_xor(acc, 8);

    if (q == 0) {
      const float hn = tanhf(xwv + acc);
      const unsigned long long pk =
          ((unsigned long long)(unsigned)t << 32) |
          (unsigned long long)(unsigned)__float_as_uint(hn);
      __hip_atomic_store(&pb[(size_t)cur * (B_ * H_) + jg], pk,
                         __ATOMIC_RELAXED, __HIP_MEMORY_SCOPE_AGENT);
      hs[((size_t)b * S_ + t) * H_ + jg] = hn;
    }
    // prefetch next xw while partners compute/publish
    const int tn = (t + 1 < S_) ? t + 1 : t;
    const float xw_next = xw[((size_t)b * S_ + tn) * H_ + jg];

    if (t + 1 < S_) {
      // stage h_{t+1}: thread tid polls h word k=tid of its batch
      const unsigned long long* src = &pb[(size_t)cur * (B_ * H_) + tid];
      unsigned long long v = pload(src);
      while ((unsigned)(v >> 32) != (unsigned)t) v = pload(src);
      const int qd = tid >> 5, i4d = (tid & 31) >> 2, e = tid & 3;
      ((float*)&hp[cur ^ 1][i4d * 16 + qd])[e] = __uint_as_float((unsigned)v);
    }
    xwv = xw_next;
    __syncthreads();
  }
}

// ---------------------------------------------------------------------------
// K5: split f32 -> bf16 hi + bf16 lo (RTN both; lo = f - hi).
// ---------------------------------------------------------------------------
__device__ __forceinline__ unsigned short bf16_rtn(float f) {
  unsigned u = __float_as_uint(f);
  return (unsigned short)((u + 0x7FFFu + ((u >> 16) & 1u)) >> 16);
}
__global__ __launch_bounds__(256) void k5_split(const float* __restrict__ src,
                                                unsigned short* __restrict__ hi,
                                                unsigned short* __restrict__ lo,
                                                int n4) {
  const int i = blockIdx.x * 256 + threadIdx.x;
  if (i >= n4) return;
  const float4 f = *(const float4*)&src[i * 4];
  unsigned short h[4], l[4];
  const float ff[4] = {f.x, f.y, f.z, f.w};
#pragma unroll
  for (int k = 0; k < 4; ++k) {
    h[k] = bf16_rtn(ff[k]);
    const float fh = __uint_as_float((unsigned)h[k] << 16);
    l[k] = bf16_rtn(ff[k] - fh);
  }
  *(ushort4*)&hi[i * 4] = make_ushort4(h[0], h[1], h[2], h[3]);
  *(ushort4*)&lo[i * 4] = make_ushort4(l[0], l[1], l[2], l[3]);
}

// ---------------------------------------------------------------------------
// K3: logits = hs @ W_fc^T + b_fc via bf16 hi/lo split MFMA (hh+hl+lh).
// 128x128 tile, 2x2 waves, 64x64/wave, BK=32, LDS row stride 40 shorts.
// ---------------------------------------------------------------------------
__global__ __launch_bounds__(256) void k3_logits(
    const unsigned short* __restrict__ Ahi, const unsigned short* __restrict__ Alo,
    const unsigned short* __restrict__ Bhi, const unsigned short* __restrict__ Blo,
    const float* __restrict__ b_fc, float* __restrict__ out) {
  __shared__ unsigned short Ah[128 * 40], Al[128 * 40];
  __shared__ unsigned short Bh[128 * 40], Bl[128 * 40];
  const int m0 = blockIdx.x * 128;
  const int n0 = blockIdx.y * 128;
  const int tid = threadIdx.x;
  const int lane = tid & 63;
  const int wave = tid >> 6;
  const int wm = wave >> 1, wn = wave & 1;
  const int lr = lane & 15;
  const int lk = (lane >> 4) * 8;

  f32x4 acc[4][4];
#pragma unroll
  for (int mi = 0; mi < 4; ++mi)
#pragma unroll
    for (int ni = 0; ni < 4; ++ni) acc[mi][ni] = (f32x4)0.0f;

  const int sr = tid >> 2;
  const int sq = (tid & 3) * 8;

  for (int k0 = 0; k0 < H_; k0 += 32) {
    __syncthreads();
#pragma unroll
    for (int it = 0; it < 2; ++it) {
      const int r = sr + it * 64;
      const size_t am = (size_t)(m0 + r) * H_ + k0 + sq;
      const int brow = (n0 + r < V_) ? (n0 + r) : (V_ - 1);
      const size_t bm = (size_t)brow * H_ + k0 + sq;
      *(float4*)&Ah[r * 40 + sq] = *(const float4*)&Ahi[am];
      *(float4*)&Al[r * 40 + sq] = *(const float4*)&Alo[am];
      *(float4*)&Bh[r * 40 + sq] = *(const float4*)&Bhi[bm];
      *(float4*)&Bl[r * 40 + sq] = *(const float4*)&Blo[bm];
    }
    __syncthreads();

    bf16x8 ah[4], al[4], bh[4], bl[4];
#pragma unroll
    for (int i = 0; i < 4; ++i) {
      ah[i] = *(const bf16x8*)&Ah[(wm * 64 + i * 16 + lr) * 40 + lk];
      al[i] = *(const bf16x8*)&Al[(wm * 64 + i * 16 + lr) * 40 + lk];
      bh[i] = *(const bf16x8*)&Bh[(wn * 64 + i * 16 + lr) * 40 + lk];
      bl[i] = *(const bf16x8*)&Bl[(wn * 64 + i * 16 + lr) * 40 + lk];
    }
#pragma unroll
    for (int mi = 0; mi < 4; ++mi)
#pragma unroll
      for (int ni = 0; ni < 4; ++ni) {
        acc[mi][ni] = __builtin_amdgcn_mfma_f32_16x16x32_bf16(
            ah[mi], bh[ni], acc[mi][ni], 0, 0, 0);
        acc[mi][ni] = __builtin_amdgcn_mfma_f32_16x16x32_bf16(
            ah[mi], bl[ni], acc[mi][ni], 0, 0, 0);
        acc[mi][ni] = __builtin_amdgcn_mfma_f32_16x16x32_bf16(
            al[mi], bh[ni], acc[mi][ni], 0, 0, 0);
      }
  }

#pragma unroll
  for (int ni = 0; ni < 4; ++ni) {
    const int v = n0 + wn * 64 + ni * 16 + lr;
    if (v >= V_) continue;
    const float bias = b_fc[v];
#pragma unroll
    for (int mi = 0; mi < 4; ++mi) {
      const int mrow = m0 + wm * 64 + mi * 16 + (lane >> 4) * 4;
#pragma unroll
      for (int r = 0; r < 4; ++r)
        out[(size_t)(mrow + r) * V_ + v] = acc[mi][ni][r] + bias;
    }
  }
}

// ---------------------------------------------------------------------------
// K4a: per-(b,v) online max+sum over S; stores (m, 1/sum).
// ---------------------------------------------------------------------------
__global__ __launch_bounds__(256) void k4_stats(const float* __restrict__ logits,
                                                float* __restrict__ stats) {
  const int g = blockIdx.x * 256 + threadIdx.x;
  const int b = g / V_;
  const int v = g - b * V_;
  const float* p = logits + (size_t)b * S_ * V_ + v;
  float m = -3.4e38f, sum = 0.f;
  for (int s = 0; s < S_; ++s) {
    const float xv = p[(size_t)s * V_];
    if (xv > m) {
      sum = sum * __expf(m - xv) + 1.f;
      m = xv;
    } else {
      sum += __expf(xv - m);
    }
  }
  stats[2 * g] = m;
  stats[2 * g + 1] = 1.f / sum;
}

// ---------------------------------------------------------------------------
// K4b: in-place normalize: out = exp(l - m) * inv_sum
// ---------------------------------------------------------------------------
__global__ __launch_bounds__(256) void k4_norm(float* __restrict__ logits,
                                               const float* __restrict__ stats) {
  const size_t idx = (size_t)blockIdx.x * 256 + threadIdx.x;
  const int v = (int)(idx % V_);
  const int b = (int)(idx / ((size_t)S_ * V_));
  const int g = b * V_ + v;
  const float m = stats[2 * g];
  const float inv = stats[2 * g + 1];
  logits[idx] = __expf(logits[idx] - m) * inv;
}

extern "C" void kernel_launch(void* const* d_in, const int* in_sizes, int n_in,
                              void* d_out, int out_size, void* d_ws,
                              size_t ws_size, hipStream_t stream) {
  const float* x    = (const float*)d_in[0];
  const float* W_ih = (const float*)d_in[1];
  const float* W_hh = (const float*)d_in[2];
  const float* b_ih = (const float*)d_in[3];
  const float* b_hh = (const float*)d_in[4];
  const float* W_fc = (const float*)d_in[5];
  const float* b_fc = (const float*)d_in[6];
  float* out = (float*)d_out;

  // ws layout (floats): xw | hs | stats | wfc_hi | wfc_lo
  //   part (128 KB, scan-only) ALIASES wfc_hi: k0/k2 finish before k5 runs
  //   hs_hi/hs_lo (bf16) ALIAS xw (dead after k2)
  float* ws = (float*)d_ws;
  float* xw    = ws;
  float* hs    = xw + (size_t)BS_ * H_;
  float* stats = hs + (size_t)BS_ * H_;
  unsigned short* wfc_hi = (unsigned short*)(stats + (size_t)2 * B_ * V_);
  unsigned short* wfc_lo = wfc_hi + (size_t)V_ * H_;
  unsigned long long* part = (unsigned long long*)wfc_hi;
  unsigned short* hs_hi = (unsigned short*)xw;
  unsigned short* hs_lo = hs_hi + (size_t)BS_ * H_;

  k0_init<<<(2 * B_ * H_) / 256, 256, 0, stream>>>(part);
  k1_xw<<<dim3(BS_ / 16, H_ / 16), 256, 0, stream>>>(x, W_ih, b_ih, b_hh, xw);
  k2_scan<<<NBLK, 512, 0, stream>>>(xw, W_hh, hs, part);
  k5_split<<<((V_ * H_ / 4) + 255) / 256, 256, 0, stream>>>(W_fc, wfc_hi,
                                                            wfc_lo, V_ * H_ / 4);
  k5_split<<<((BS_ * H_ / 4) + 255) / 256, 256, 0, stream>>>(
      hs, hs_hi, hs_lo, BS_ * H_ / 4);
  k3_logits<<<dim3(BS_ / 128, (V_ + 127) / 128), 256, 0, stream>>>(
      hs_hi, hs_lo, wfc_hi, wfc_lo, b_fc, out);
  k4_stats<<<(B_ * V_) / 256, 256, 0, stream>>>(out, stats);
  k4_norm<<<(int)((size_t)BS_ * V_ / 256), 256, 0, stream>>>(out, stats);
}

// Round 8
// 1654.717 us; speedup vs baseline: 1.3419x; 1.2325x over previous
//
#include <hip/hip_runtime.h>
#include <hip/hip_bf16.h>
#include <math.h>

#define B_ 16
#define S_ 512
#define E_ 300
#define H_ 512
#define V_ 10000
#define BS_ (B_ * S_)  // 8192

#define NSL 16           // slices (blocks) per batch, j-split
#define JPB (H_ / NSL)   // 32 output rows per block
#define NBLK (B_ * NSL)  // 256 blocks in the scan

typedef __attribute__((ext_vector_type(4))) float f32x4;
typedef __attribute__((ext_vector_type(8))) short bf16x8;

// ---------------------------------------------------------------------------
// K0: invalidate exchange tags in BOTH mailboxes (fast sc0 + safe sc1).
// 2 mailboxes x 2 slots x B x H u64 = 32768 words.
// ---------------------------------------------------------------------------
__global__ __launch_bounds__(256) void k0_init(unsigned long long* __restrict__ part) {
  const int idx = blockIdx.x * 256 + threadIdx.x;
  part[idx] = 0xFFFFFFFF00000000ull;
}

// ---------------------------------------------------------------------------
// K1: xw[bs,h] = sum_e x[bs,e] * W_ih[h,e] + b_ih[h] + b_hh[h]
// ---------------------------------------------------------------------------
__global__ __launch_bounds__(256) void k1_xw(const float* __restrict__ x,
                                             const float* __restrict__ W_ih,
                                             const float* __restrict__ b_ih,
                                             const float* __restrict__ b_hh,
                                             float* __restrict__ xw) {
  __shared__ float As[16][301];
  __shared__ float Ws[16][301];
  const int row0 = blockIdx.x * 16;
  const int col0 = blockIdx.y * 16;
  const int tid = threadIdx.x;
  for (int idx = tid; idx < 16 * E_; idx += 256) {
    int r = idx / E_, c = idx - r * E_;
    As[r][c] = x[(size_t)(row0 + r) * E_ + c];
    Ws[r][c] = W_ih[(size_t)(col0 + r) * E_ + c];
  }
  __syncthreads();
  const int i = tid >> 4, j = tid & 15;
  float acc = 0.f;
#pragma unroll 4
  for (int e = 0; e < E_; ++e) acc += As[i][e] * Ws[j][e];
  const int h = col0 + j;
  xw[(size_t)(row0 + i) * H_ + h] = acc + b_ih[h] + b_hh[h];
}

// sc1 (MALL-coherent) relaxed atomic load — the always-correct path
__device__ __forceinline__ unsigned long long pload(
    const unsigned long long* p) {
  return __hip_atomic_load(p, __ATOMIC_RELAXED, __HIP_MEMORY_SCOPE_AGENT);
}
// sc0 (L1-bypass, L2-point) load/store — fast path when producer+consumer
// share an XCD (per-XCD L2 is coherent; vector L1 is write-through).
__device__ __forceinline__ unsigned long long load_sc0(
    const unsigned long long* p) {
  unsigned long long r;
  asm volatile("global_load_dwordx2 %0, %1, off sc0\n\ts_waitcnt vmcnt(0)"
               : "=v"(r) : "v"(p) : "memory");
  return r;
}
__device__ __forceinline__ void store_sc0(unsigned long long* p,
                                          unsigned long long v) {
  asm volatile("global_store_dwordx2 %0, %1, off sc0" :: "v"(p), "v"(v)
               : "memory");
}

// ---------------------------------------------------------------------------
// K2: scan, j-split, LDS-resident W, XCD-local h exchange.
// Mapping: b = blockIdx&15, g = blockIdx>>4 -> if dispatch round-robins
// XCDs by blockIdx%8 (measured m09 convention), ALL 16 blocks of batch b
// land on XCD b%8 and exchange through their shared L2 (sc0, ~250 cy RT)
// instead of the MALL (sc1, ~1000 cy RT, rounds 3-7's residual).
// Publisher (q==0) writes its tagged u64 (t<<32|f32(h)) to BOTH mailboxes:
// fast (sc0) and safe (sc1). Consumers poll fast up to 64x, then STICKILY
// downgrade that thread to the safe word — correct for any dispatch
// placement (tags never falsely match; safe copy always arrives).
// Staging remap: thread tid polls h word k(tid) = ((tid&63)>>2)*32 +
// (tid>>6)*4 + (tid&3) so its LDS write lands at word = tid (linear,
// conflict-free), while the dot keeps the i4-major layout
// (word = i4*64 + q*4 + e) whose reads are 2-way-broadcast (free).
// ---------------------------------------------------------------------------
__global__ __launch_bounds__(512) void k2_scan(
    const float* __restrict__ xw, const float* __restrict__ W_hh,
    float* __restrict__ hs, unsigned long long* __restrict__ part) {
  const int b = blockIdx.x & 15;  // batch -> XCD b%8 under round-robin
  const int g = blockIdx.x >> 4;  // slice
  const int tid = threadIdx.x;
  const int j = tid >> 4;         // 0..31 row within slice
  const int q = tid & 15;         // k-sixteenth
  const int jg = g * JPB + j;     // global output row

  __shared__ f32x4 Wp[8 * 512];   // 64 KB, instruction-major W
  __shared__ f32x4 hp4[2][128];   // 4 KB, double-buffered h (i4-major)

  {
    const float* wrow = &W_hh[(size_t)jg * H_ + q * 32];
#pragma unroll
    for (int i4 = 0; i4 < 8; ++i4)
      Wp[i4 * 512 + tid] = *(const f32x4*)&wrow[i4 * 4];
  }
  if (tid < 128) hp4[0][tid] = (f32x4)0.f;

  // mailboxes: [slot][b][word]; fast first 2*B*H words, safe next 2*B*H
  unsigned long long* const pf = part + (size_t)b * H_;
  unsigned long long* const ps = part + (size_t)2 * B_ * H_ + (size_t)b * H_;
  // poll word for this thread (see remap comment)
  const int kk = ((tid & 63) >> 2) * 32 + (tid >> 6) * 4 + (tid & 3);
  bool fast = true;

  float xwv = xw[(size_t)b * S_ * H_ + jg];  // t = 0
  __syncthreads();

  for (int t = 0; t < S_; ++t) {
    const int cur = t & 1;
    // dot: 8 x (b128 W read, b128 h broadcast, fma4)
    f32x4 a4 = (f32x4)0.f;
#pragma unroll
    for (int i4 = 0; i4 < 8; ++i4) {
      const f32x4 wv = Wp[i4 * 512 + tid];
      const f32x4 hv = hp4[cur][i4 * 16 + q];
      a4 += wv * hv;
    }
    float acc = a4.x + a4.y + a4.z + a4.w;
    acc += __shfl_xor(acc, 1);
    acc += __shfl_xor(acc, 2);
    acc += __shfl_xor(acc, 4);
    acc += __shfl_xor(acc, 8);

    if (q == 0) {
      const float hn = tanhf(xwv + acc);
      const unsigned long long pk =
          ((unsigned long long)(unsigned)t << 32) |
          (unsigned long long)(unsigned)__float_as_uint(hn);
      store_sc0(&pf[(size_t)cur * (B_ * H_) + jg], pk);
      __hip_atomic_store(&ps[(size_t)cur * (B_ * H_) + jg], pk,
                         __ATOMIC_RELAXED, __HIP_MEMORY_SCOPE_AGENT);
      hs[((size_t)b * S_ + t) * H_ + jg] = hn;
    }
    // prefetch next xw while partners compute/publish
    const int tn = (t + 1 < S_) ? t + 1 : t;
    const float xw_next = xw[((size_t)b * S_ + tn) * H_ + jg];

    if (t + 1 < S_) {
      unsigned long long v = 0;
      bool got = false;
      const unsigned long long* fs = &pf[(size_t)cur * (B_ * H_) + kk];
      if (fast) {
        for (int it = 0; it < 64; ++it) {
          v = load_sc0(fs);
          if ((unsigned)(v >> 32) == (unsigned)t) { got = true; break; }
        }
        if (!got) fast = false;  // sticky downgrade (cross-XCD placement)
      }
      if (!got) {
        const unsigned long long* ss = &ps[(size_t)cur * (B_ * H_) + kk];
        v = pload(ss);
        while ((unsigned)(v >> 32) != (unsigned)t) v = pload(ss);
      }
      ((float*)&hp4[cur ^ 1][0])[tid] = __uint_as_float((unsigned)v);
    }
    xwv = xw_next;
    __syncthreads();
  }
}

// ---------------------------------------------------------------------------
// K5: split f32 -> bf16 hi + bf16 lo (RTN both; lo = f - hi).
// ---------------------------------------------------------------------------
__device__ __forceinline__ unsigned short bf16_rtn(float f) {
  unsigned u = __float_as_uint(f);
  return (unsigned short)((u + 0x7FFFu + ((u >> 16) & 1u)) >> 16);
}
__global__ __launch_bounds__(256) void k5_split(const float* __restrict__ src,
                                                unsigned short* __restrict__ hi,
                                                unsigned short* __restrict__ lo,
                                                int n4) {
  const int i = blockIdx.x * 256 + threadIdx.x;
  if (i >= n4) return;
  const float4 f = *(const float4*)&src[i * 4];
  unsigned short h[4], l[4];
  const float ff[4] = {f.x, f.y, f.z, f.w};
#pragma unroll
  for (int k = 0; k < 4; ++k) {
    h[k] = bf16_rtn(ff[k]);
    const float fh = __uint_as_float((unsigned)h[k] << 16);
    l[k] = bf16_rtn(ff[k] - fh);
  }
  *(ushort4*)&hi[i * 4] = make_ushort4(h[0], h[1], h[2], h[3]);
  *(ushort4*)&lo[i * 4] = make_ushort4(l[0], l[1], l[2], l[3]);
}

// ---------------------------------------------------------------------------
// K3: logits = hs @ W_fc^T + b_fc via bf16 hi/lo split MFMA (hh+hl+lh).
// 128x128 tile, 2x2 waves, 64x64/wave, BK=32, LDS row stride 40 shorts.
// ---------------------------------------------------------------------------
__global__ __launch_bounds__(256) void k3_logits(
    const unsigned short* __restrict__ Ahi, const unsigned short* __restrict__ Alo,
    const unsigned short* __restrict__ Bhi, const unsigned short* __restrict__ Blo,
    const float* __restrict__ b_fc, float* __restrict__ out) {
  __shared__ unsigned short Ah[128 * 40], Al[128 * 40];
  __shared__ unsigned short Bh[128 * 40], Bl[128 * 40];
  const int m0 = blockIdx.x * 128;
  const int n0 = blockIdx.y * 128;
  const int tid = threadIdx.x;
  const int lane = tid & 63;
  const int wave = tid >> 6;
  const int wm = wave >> 1, wn = wave & 1;
  const int lr = lane & 15;
  const int lk = (lane >> 4) * 8;

  f32x4 acc[4][4];
#pragma unroll
  for (int mi = 0; mi < 4; ++mi)
#pragma unroll
    for (int ni = 0; ni < 4; ++ni) acc[mi][ni] = (f32x4)0.0f;

  const int sr = tid >> 2;
  const int sq = (tid & 3) * 8;

  for (int k0 = 0; k0 < H_; k0 += 32) {
    __syncthreads();
#pragma unroll
    for (int it = 0; it < 2; ++it) {
      const int r = sr + it * 64;
      const size_t am = (size_t)(m0 + r) * H_ + k0 + sq;
      const int brow = (n0 + r < V_) ? (n0 + r) : (V_ - 1);
      const size_t bm = (size_t)brow * H_ + k0 + sq;
      *(float4*)&Ah[r * 40 + sq] = *(const float4*)&Ahi[am];
      *(float4*)&Al[r * 40 + sq] = *(const float4*)&Alo[am];
      *(float4*)&Bh[r * 40 + sq] = *(const float4*)&Bhi[bm];
      *(float4*)&Bl[r * 40 + sq] = *(const float4*)&Blo[bm];
    }
    __syncthreads();

    bf16x8 ah[4], al[4], bh[4], bl[4];
#pragma unroll
    for (int i = 0; i < 4; ++i) {
      ah[i] = *(const bf16x8*)&Ah[(wm * 64 + i * 16 + lr) * 40 + lk];
      al[i] = *(const bf16x8*)&Al[(wm * 64 + i * 16 + lr) * 40 + lk];
      bh[i] = *(const bf16x8*)&Bh[(wn * 64 + i * 16 + lr) * 40 + lk];
      bl[i] = *(const bf16x8*)&Bl[(wn * 64 + i * 16 + lr) * 40 + lk];
    }
#pragma unroll
    for (int mi = 0; mi < 4; ++mi)
#pragma unroll
      for (int ni = 0; ni < 4; ++ni) {
        acc[mi][ni] = __builtin_amdgcn_mfma_f32_16x16x32_bf16(
            ah[mi], bh[ni], acc[mi][ni], 0, 0, 0);
        acc[mi][ni] = __builtin_amdgcn_mfma_f32_16x16x32_bf16(
            ah[mi], bl[ni], acc[mi][ni], 0, 0, 0);
        acc[mi][ni] = __builtin_amdgcn_mfma_f32_16x16x32_bf16(
            al[mi], bh[ni], acc[mi][ni], 0, 0, 0);
      }
  }

#pragma unroll
  for (int ni = 0; ni < 4; ++ni) {
    const int v = n0 + wn * 64 + ni * 16 + lr;
    if (v >= V_) continue;
    const float bias = b_fc[v];
#pragma unroll
    for (int mi = 0; mi < 4; ++mi) {
      const int mrow = m0 + wm * 64 + mi * 16 + (lane >> 4) * 4;
#pragma unroll
      for (int r = 0; r < 4; ++r)
        out[(size_t)(mrow + r) * V_ + v] = acc[mi][ni][r] + bias;
    }
  }
}

// ---------------------------------------------------------------------------
// K4a: per-(b,v) online max+sum over S; stores (m, 1/sum).
// ---------------------------------------------------------------------------
__global__ __launch_bounds__(256) void k4_stats(const float* __restrict__ logits,
                                                float* __restrict__ stats) {
  const int g = blockIdx.x * 256 + threadIdx.x;
  const int b = g / V_;
  const int v = g - b * V_;
  const float* p = logits + (size_t)b * S_ * V_ + v;
  float m = -3.4e38f, sum = 0.f;
  for (int s = 0; s < S_; ++s) {
    const float xv = p[(size_t)s * V_];
    if (xv > m) {
      sum = sum * __expf(m - xv) + 1.f;
      m = xv;
    } else {
      sum += __expf(xv - m);
    }
  }
  stats[2 * g] = m;
  stats[2 * g + 1] = 1.f / sum;
}

// ---------------------------------------------------------------------------
// K4b: in-place normalize: out = exp(l - m) * inv_sum
// ---------------------------------------------------------------------------
__global__ __launch_bounds__(256) void k4_norm(float* __restrict__ logits,
                                               const float* __restrict__ stats) {
  const size_t idx = (size_t)blockIdx.x * 256 + threadIdx.x;
  const int v = (int)(idx % V_);
  const int b = (int)(idx / ((size_t)S_ * V_));
  const int g = b * V_ + v;
  const float m = stats[2 * g];
  const float inv = stats[2 * g + 1];
  logits[idx] = __expf(logits[idx] - m) * inv;
}

extern "C" void kernel_launch(void* const* d_in, const int* in_sizes, int n_in,
                              void* d_out, int out_size, void* d_ws,
                              size_t ws_size, hipStream_t stream) {
  const float* x    = (const float*)d_in[0];
  const float* W_ih = (const float*)d_in[1];
  const float* W_hh = (const float*)d_in[2];
  const float* b_ih = (const float*)d_in[3];
  const float* b_hh = (const float*)d_in[4];
  const float* W_fc = (const float*)d_in[5];
  const float* b_fc = (const float*)d_in[6];
  float* out = (float*)d_out;

  // ws layout (floats): xw | hs | stats | wfc_hi | wfc_lo
  //   part (256 KB = fast+safe mailboxes, scan-only) ALIASES wfc_hi
  //   hs_hi/hs_lo (bf16) ALIAS xw (dead after k2)
  float* ws = (float*)d_ws;
  float* xw    = ws;
  float* hs    = xw + (size_t)BS_ * H_;
  float* stats = hs + (size_t)BS_ * H_;
  unsigned short* wfc_hi = (unsigned short*)(stats + (size_t)2 * B_ * V_);
  unsigned short* wfc_lo = wfc_hi + (size_t)V_ * H_;
  unsigned long long* part = (unsigned long long*)wfc_hi;
  unsigned short* hs_hi = (unsigned short*)xw;
  unsigned short* hs_lo = hs_hi + (size_t)BS_ * H_;

  k0_init<<<(4 * B_ * H_) / 256, 256, 0, stream>>>(part);
  k1_xw<<<dim3(BS_ / 16, H_ / 16), 256, 0, stream>>>(x, W_ih, b_ih, b_hh, xw);
  k2_scan<<<NBLK, 512, 0, stream>>>(xw, W_hh, hs, part);
  k5_split<<<((V_ * H_ / 4) + 255) / 256, 256, 0, stream>>>(W_fc, wfc_hi,
                                                            wfc_lo, V_ * H_ / 4);
  k5_split<<<((BS_ * H_ / 4) + 255) / 256, 256, 0, stream>>>(
      hs, hs_hi, hs_lo, BS_ * H_ / 4);
  k3_logits<<<dim3(BS_ / 128, (V_ + 127) / 128), 256, 0, stream>>>(
      hs_hi, hs_lo, wfc_hi, wfc_lo, b_fc, out);
  k4_stats<<<(B_ * V_) / 256, 256, 0, stream>>>(out, stats);
  k4_norm<<<(int)((size_t)BS_ * V_ / 256), 256, 0, stream>>>(out, stats);
}